// Round 7
// baseline (2895.242 us; speedup 1.0000x reference)
//
#include <hip/hip_runtime.h>
#include <cstdint>
#include <cstddef>

typedef _Float16 f16;
typedef _Float16 f16x4 __attribute__((ext_vector_type(4)));
typedef _Float16 f16x8 __attribute__((ext_vector_type(8)));
typedef float f32x4 __attribute__((ext_vector_type(4)));

#define LRELU_SLOPE 0.2f

#define GLL16(g, l)                                                          \
  __builtin_amdgcn_global_load_lds(                                          \
      (const __attribute__((address_space(1))) void*)(g),                    \
      (__attribute__((address_space(3))) void*)(l), 16, 0, 0)

// ---------------- prep: x (f32) -> x_h (f16), padded rows zeroed ----------------
__global__ __launch_bounds__(256) void k_prep_xh(const float* __restrict__ x,
                                                 f16* __restrict__ xh,
                                                 int nvalid, int npad) {
  int total = npad * 192;
  for (int idx = blockIdx.x * blockDim.x + threadIdx.x; idx < total;
       idx += gridDim.x * blockDim.x) {
    int row = idx / 192;
    f16x4 o;
    if (row < nvalid) {
      const float4 v = *(const float4*)(x + (size_t)idx * 4);
      o[0] = (f16)v.x; o[1] = (f16)v.y; o[2] = (f16)v.z; o[3] = (f16)v.w;
    } else {
      o[0] = (f16)0.f; o[1] = (f16)0.f; o[2] = (f16)0.f; o[3] = (f16)0.f;
    }
    *(f16x4*)(xh + (size_t)idx * 4) = o;
  }
}

// ---------------- both W [768][768] f32 -> Wt [n][k] f16, one launch ----------------
__global__ __launch_bounds__(256) void k_transpose_w2(const float* __restrict__ W1,
                                                      const float* __restrict__ W2,
                                                      f16* __restrict__ Wt1,
                                                      f16* __restrict__ Wt2) {
  const float* W = blockIdx.z ? W2 : W1;
  f16* Wt = blockIdx.z ? Wt2 : Wt1;
  __shared__ float tile[32][33];
  int bn = blockIdx.x * 32;
  int bk = blockIdx.y * 32;
  int tx = threadIdx.x & 31, ty = threadIdx.x >> 5;
  #pragma unroll
  for (int r = ty; r < 32; r += 8)
    tile[r][tx] = W[(size_t)(bk + r) * 768 + bn + tx];
  __syncthreads();
  #pragma unroll
  for (int r = ty; r < 32; r += 8)
    Wt[(size_t)(bn + r) * 768 + bk + tx] = (f16)tile[tx][r];
}

// ---------------- CSR build ----------------
__global__ void k_hist(const int* __restrict__ dst, int E, int* __restrict__ counts) {
  for (int e = blockIdx.x * blockDim.x + threadIdx.x; e < E;
       e += gridDim.x * blockDim.x) atomicAdd(&counts[dst[e]], 1);
}

__global__ __launch_bounds__(1024) void k_scan_block(const int* __restrict__ counts,
                                                     int* __restrict__ starts,
                                                     int* __restrict__ cursor, int n) {
  const int t = threadIdx.x;
  const int nthr = 1024;
  const int chunk = (n + nthr - 1) / nthr;
  const int base = t * chunk;
  int tsum = 0;
  for (int i = 0; i < chunk; i++) {
    int idx = base + i;
    if (idx < n) tsum += counts[idx];
  }
  int lane = t & 63, wv = t >> 6;
  int s = tsum;
  #pragma unroll
  for (int off = 1; off < 64; off <<= 1) {
    int tmp = __shfl_up(s, off);
    if (lane >= off) s += tmp;
  }
  __shared__ int wsum[16];
  if (lane == 63) wsum[wv] = s;
  __syncthreads();
  int woff = 0;
  for (int w = 0; w < wv; w++) woff += wsum[w];
  int run = woff + s - tsum;
  for (int i = 0; i < chunk; i++) {
    int idx = base + i;
    if (idx < n) {
      starts[idx] = run;
      cursor[idx] = run;
      run += counts[idx];
    }
  }
  if (t == nthr - 1) starts[n] = run;
}

__global__ void k_fill(const int* __restrict__ src, const int* __restrict__ dst, int E,
                       int* __restrict__ cursor, int* __restrict__ src_sorted,
                       int* __restrict__ dst_sorted) {
  for (int e = blockIdx.x * blockDim.x + threadIdx.x; e < E;
       e += gridDim.x * blockDim.x) {
    int slot = atomicAdd(&cursor[dst[e]], 1);
    src_sorted[slot] = src[e];
    dst_sorted[slot] = dst[e];
  }
}

// ---------------- fp16 MFMA GEMM, BK=64, global_load_lds, slice-major C ----------
// LDS: 128 rows x 64 f16; swizzle phys_chunk = logical ^ (row&7).
// C layout: [8 slices][Mpad][96] f16, SS = slice stride (round-3-verified epilogue).
__global__ __launch_bounds__(256) void k_gemm_f16(const f16* __restrict__ A,
                                                  const f16* __restrict__ Bt,
                                                  f16* __restrict__ C, int Mvalid,
                                                  int SS) {
  __shared__ __align__(16) f16 As[8192];
  __shared__ __align__(16) f16 Bs[8192];
  const int K = 768;
  const int tid = threadIdx.x;
  const int bm = blockIdx.x * 128;
  const int bn = blockIdx.y * 128;
  const int lane = tid & 63;
  const int wave = tid >> 6;
  const int wr = (wave >> 1) * 64;
  const int wc = (wave & 1) * 64;

  size_t goffA[4], goffB[4];
  #pragma unroll
  for (int p = 0; p < 4; p++) {
    const int cell = p * 256 + tid;
    const int row = cell >> 3;
    const int cl = (cell & 7) ^ (row & 7);
    goffA[p] = (size_t)(bm + row) * K + cl * 8;
    goffB[p] = (size_t)(bn + row) * K + cl * 8;
  }

  f32x4 acc[4][4];
  const f32x4 vzero = {0.f, 0.f, 0.f, 0.f};
  #pragma unroll
  for (int i = 0; i < 4; i++)
    #pragma unroll
    for (int j = 0; j < 4; j++) acc[i][j] = vzero;

  const int fr = lane & 15;
  const int fq = lane >> 4;

  for (int k0 = 0; k0 < K; k0 += 64) {
    #pragma unroll
    for (int p = 0; p < 4; p++) GLL16(A + goffA[p] + k0, As + p * 2048 + wave * 512);
    #pragma unroll
    for (int p = 0; p < 4; p++) GLL16(Bt + goffB[p] + k0, Bs + p * 2048 + wave * 512);
    __syncthreads();
    #pragma unroll
    for (int ks = 0; ks < 2; ks++) {
      f16x8 af[4], bf[4];
      #pragma unroll
      for (int i = 0; i < 4; i++) {
        const int r = wr + i * 16 + fr;
        const int phys = (ks * 4 + fq) ^ (r & 7);
        af[i] = *(const f16x8*)(&As[r * 64 + phys * 8]);
      }
      #pragma unroll
      for (int j = 0; j < 4; j++) {
        const int r = wc + j * 16 + fr;
        const int phys = (ks * 4 + fq) ^ (r & 7);
        bf[j] = *(const f16x8*)(&Bs[r * 64 + phys * 8]);
      }
      #pragma unroll
      for (int i = 0; i < 4; i++)
        #pragma unroll
        for (int j = 0; j < 4; j++)
          acc[i][j] = __builtin_amdgcn_mfma_f32_16x16x32_f16(af[i], bf[j], acc[i][j], 0, 0, 0);
    }
    __syncthreads();
  }

  #pragma unroll
  for (int i = 0; i < 4; i++) {
    #pragma unroll
    for (int j = 0; j < 4; j++) {
      const int col = bn + wc + j * 16 + fr;
      const int cs = col / 96;
      const int cw = col - cs * 96;
      f16* cp = C + (size_t)cs * SS + cw;
      #pragma unroll
      for (int r = 0; r < 4; r++) {
        const int row = bm + wr + i * 16 + fq * 4 + r;
        if (row < Mvalid) cp[(size_t)row * 96] = (f16)acc[i][j][r];
      }
    }
  }
}

// ---------------- attention logits from slice-major h (round-3-verified) ---------
template <int H>
__global__ __launch_bounds__(256) void k_al(const f16* __restrict__ hs,
                                            const float* __restrict__ a_src,
                                            const float* __restrict__ a_dst,
                                            float* __restrict__ als,
                                            float* __restrict__ ald, int N, int SS) {
  int node = blockIdx.x * 4 + (threadIdx.x >> 6);
  int lane = threadIdx.x & 63;
  if (node >= N) return;
  const int sl = lane >> 3, wl = lane & 7;
  const f16* hp = hs + (size_t)sl * SS + (size_t)node * 96 + wl * 12;
  float ss = 0.f, sd = 0.f;
  const int cbase = sl * 96 + wl * 12;
  #pragma unroll
  for (int q = 0; q < 3; q++) {
    f16x4 hv = *(const f16x4*)(hp + q * 4);
    #pragma unroll
    for (int j = 0; j < 4; j++) {
      int c = cbase + q * 4 + j;
      float v = (float)hv[j];
      ss += v * a_src[c];
      sd += v * a_dst[c];
    }
  }
  const int red = (H == 8) ? 8 : 64;
  #pragma unroll
  for (int off = 1; off < red; off <<= 1) {
    ss += __shfl_xor(ss, off);
    sd += __shfl_xor(sd, off);
  }
  if (H == 8) {
    if ((lane & 7) == 0) {
      als[(size_t)node * 8 + sl] = ss;
      ald[(size_t)node * 8 + sl] = sd;
    }
  } else {
    if (lane == 0) { als[node] = ss; ald[node] = sd; }
  }
}

// ---------------- edge-parallel exp(leaky_relu(logit)) on SORTED edges ----------
// head-major planes ex[H][E] (round-5-verified)
template <int H>
__global__ __launch_bounds__(256) void k_alpha(const float* __restrict__ als,
                                               const float* __restrict__ ald,
                                               const int* __restrict__ srcs,
                                               const int* __restrict__ dsts,
                                               float* __restrict__ ex, int E) {
  const int e = blockIdx.x * 256 + threadIdx.x;
  if (e >= E) return;
  const int s = srcs[e], d = dsts[e];
  #pragma unroll
  for (int h = 0; h < H; h++) {
    float v = als[(size_t)s * H + h] + ald[(size_t)d * H + h];
    v = v > 0.f ? v : LRELU_SLOPE * v;
    ex[(size_t)h * E + e] = __expf(v);
  }
}

// ---------------- per-node zinv from ex planes via CSR ----------------
template <int H>
__global__ __launch_bounds__(256) void k_z(const float* __restrict__ ex,
                                           const int* __restrict__ starts,
                                           float* __restrict__ zinv, int N, int E) {
  int node = blockIdx.x * 4 + (threadIdx.x >> 6);
  int lane = threadIdx.x & 63;
  if (node >= N) return;
  const int start = starts[node];
  const int deg = starts[node + 1] - start;
  float z = 0.f;
  if (H == 8) {
    const int h = lane & 7;
    const float* exh = ex + (size_t)h * E + start;
    for (int j = lane >> 3; j < deg; j += 8) z += exh[j];
    #pragma unroll
    for (int off = 8; off < 64; off <<= 1) z += __shfl_xor(z, off);
    if (lane < 8) zinv[(size_t)node * 8 + h] = 1.f / (z + 1e-16f);
  } else {
    const float* exh = ex + start;
    for (int j = lane; j < deg; j += 64) z += exh[j];
    #pragma unroll
    for (int off = 1; off < 64; off <<= 1) z += __shfl_xor(z, off);
    if (lane == 0) zinv[node] = 1.f / (z + 1e-16f);
  }
}

// ---------------- slice-blocked segmented SpMM ----------------
// block = (32-node group g, slice s); bid = g*8+s pins slice->XCD (round-3/5
// verified mapping: per-XCD working set = 3.84MB slice, L2-resident).
// 192 thr = 8 edge-slots x 24 ch-lanes; branch-free ds_add_f32 into padded LDS;
// zinv normalization + bias (+ELU) at write-out.
template <int H, bool FINAL>
__global__ __launch_bounds__(192) void k_spmm(
    const f16* __restrict__ hs, const float* __restrict__ ex,
    const float* __restrict__ zinv, const int* __restrict__ starts,
    const int* __restrict__ srcs, const int* __restrict__ dsts,
    const float* __restrict__ bias, void* __restrict__ outv,
    int N, int SS, int E) {
  const int s = blockIdx.x & 7;
  const int g = blockIdx.x >> 3;
  const int n0 = g * 32;
  const int t = threadIdx.x;
  const int k = t / 24;
  const int c = t - k * 24;
  const int head = (H == 8) ? s : 0;

  __shared__ float s_acc[32][101];  // odd stride: decorrelate stride-4 bank pattern
  #pragma unroll 4
  for (int i = t; i < 32 * 101; i += 192) ((float*)s_acc)[i] = 0.f;
  __syncthreads();

  const f16* hsl = hs + (size_t)s * SS;
  const float* exh = ex + (size_t)head * E;
  const int e0 = starts[n0];
  const int e1 = starts[min(n0 + 32, N)];

  for (int i = e0 + k; i < e1; i += 8) {
    const float a = exh[i];
    const int sv = srcs[i];
    const int ln = dsts[i] - n0;
    const f16x4 hv = *(const f16x4*)(hsl + (size_t)sv * 96 + c * 4);
    atomicAdd(&s_acc[ln][c * 4 + 0], a * (float)hv[0]);
    atomicAdd(&s_acc[ln][c * 4 + 1], a * (float)hv[1]);
    atomicAdd(&s_acc[ln][c * 4 + 2], a * (float)hv[2]);
    atomicAdd(&s_acc[ln][c * 4 + 3], a * (float)hv[3]);
  }
  __syncthreads();

  const float4 bv = *(const float4*)(bias + s * 96 + c * 4);
  for (int ln = k; ln < 32; ln += 8) {
    const int n = n0 + ln;
    if (n >= N) break;
    const float zi = zinv[(size_t)n * H + head];
    float v0 = s_acc[ln][c * 4 + 0] * zi + bv.x;
    float v1 = s_acc[ln][c * 4 + 1] * zi + bv.y;
    float v2 = s_acc[ln][c * 4 + 2] * zi + bv.z;
    float v3 = s_acc[ln][c * 4 + 3] * zi + bv.w;
    if (FINAL) {
      float4 o = {v0, v1, v2, v3};
      *(float4*)((float*)outv + (size_t)n * 768 + s * 96 + c * 4) = o;
    } else {
      v0 = v0 > 0.f ? v0 : expm1f(v0);
      v1 = v1 > 0.f ? v1 : expm1f(v1);
      v2 = v2 > 0.f ? v2 : expm1f(v2);
      v3 = v3 > 0.f ? v3 : expm1f(v3);
      f16x4 o;
      o[0] = (f16)v0; o[1] = (f16)v1; o[2] = (f16)v2; o[3] = (f16)v3;
      *(f16x4*)((f16*)outv + (size_t)n * 768 + s * 96 + c * 4) = o;
    }
  }
}

// ---------------- launcher ----------------
extern "C" void kernel_launch(void* const* d_in, const int* in_sizes, int n_in,
                              void* d_out, int out_size, void* d_ws, size_t ws_size,
                              hipStream_t stream) {
  const float* x   = (const float*)d_in[0];
  const int*   ei  = (const int*)d_in[1];
  const float* W1  = (const float*)d_in[2];
  const float* as1 = (const float*)d_in[3];
  const float* ad1 = (const float*)d_in[4];
  const float* b1  = (const float*)d_in[5];
  const float* W2  = (const float*)d_in[6];
  const float* as2 = (const float*)d_in[7];
  const float* ad2 = (const float*)d_in[8];
  const float* b2  = (const float*)d_in[9];

  const int N = in_sizes[0] / 768;
  const int E = in_sizes[1] / 2;
  const int Mpad = (N + 127) & ~127;
  const int SS = Mpad * 96;
  const int* srcp = ei;
  const int* dstp = ei + E;

  char* p = (char*)d_ws;
  auto alloc = [&](size_t b) { char* r = p; p += (b + 255) & ~(size_t)255; return r; };
  f16*   bufX   = (f16*)alloc((size_t)Mpad * 768 * sizeof(f16));  // x_h, then out1
  f16*   bufH   = (f16*)alloc((size_t)Mpad * 768 * sizeof(f16));  // h slice-major
  f16*   Wt1    = (f16*)alloc((size_t)768 * 768 * sizeof(f16));
  f16*   Wt2    = (f16*)alloc((size_t)768 * 768 * sizeof(f16));
  float* ex     = (float*)alloc((size_t)8 * E * sizeof(float));
  float* als1   = (float*)alloc((size_t)N * 8 * sizeof(float));
  float* ald1   = (float*)alloc((size_t)N * 8 * sizeof(float));
  float* zinv1  = (float*)alloc((size_t)N * 8 * sizeof(float));
  float* als2   = (float*)alloc((size_t)N * sizeof(float));
  float* ald2   = (float*)alloc((size_t)N * sizeof(float));
  float* zinv2  = (float*)alloc((size_t)N * sizeof(float));
  int*   counts = (int*)alloc((size_t)N * sizeof(int));
  int*   starts = (int*)alloc(((size_t)N + 1) * sizeof(int));
  int*   cursor = (int*)alloc((size_t)N * sizeof(int));
  int*   srcs   = (int*)alloc((size_t)E * sizeof(int));
  int*   dsts   = (int*)alloc((size_t)E * sizeof(int));

  // CSR build
  hipMemsetAsync(counts, 0, (size_t)N * sizeof(int), stream);
  k_hist<<<dim3(512), dim3(256), 0, stream>>>(dstp, E, counts);
  k_scan_block<<<dim3(1), dim3(1024), 0, stream>>>(counts, starts, cursor, N);
  k_fill<<<dim3(512), dim3(256), 0, stream>>>(srcp, dstp, E, cursor, srcs, dsts);

  // prep
  k_prep_xh<<<dim3(1024), dim3(256), 0, stream>>>(x, bufX, N, Mpad);
  k_transpose_w2<<<dim3(24, 24, 2), dim3(256), 0, stream>>>(W1, W2, Wt1, Wt2);

  const int eb = (E + 255) / 256;
  const int ngroups = (N + 31) / 32;

  // layer 1
  k_gemm_f16<<<dim3(Mpad / 128, 6), dim3(256), 0, stream>>>(bufX, Wt1, bufH, N, SS);
  k_al<8><<<dim3((N + 3) / 4), dim3(256), 0, stream>>>(bufH, as1, ad1, als1, ald1, N, SS);
  k_alpha<8><<<dim3(eb), dim3(256), 0, stream>>>(als1, ald1, srcs, dsts, ex, E);
  k_z<8><<<dim3((N + 3) / 4), dim3(256), 0, stream>>>(ex, starts, zinv1, N, E);
  k_spmm<8, false><<<dim3(ngroups * 8), dim3(192), 0, stream>>>(
      bufH, ex, zinv1, starts, srcs, dsts, b1, bufX, N, SS, E);

  // layer 2 (bufX pad rows still hold k_prep_xh zeros)
  k_gemm_f16<<<dim3(Mpad / 128, 6), dim3(256), 0, stream>>>(bufX, Wt2, bufH, N, SS);
  k_al<1><<<dim3((N + 3) / 4), dim3(256), 0, stream>>>(bufH, as2, ad2, als2, ald2, N, SS);
  k_alpha<1><<<dim3(eb), dim3(256), 0, stream>>>(als2, ald2, srcs, dsts, ex, E);
  k_z<1><<<dim3((N + 3) / 4), dim3(256), 0, stream>>>(ex, starts, zinv2, N, E);
  k_spmm<1, true><<<dim3(ngroups * 8), dim3(192), 0, stream>>>(
      bufH, ex, zinv2, starts, srcs, dsts, b2, d_out, N, SS, E);
}

// Round 8
// 611.060 us; speedup vs baseline: 4.7381x; 4.7381x over previous
//
#include <hip/hip_runtime.h>
#include <cstdint>
#include <cstddef>

typedef _Float16 f16;
typedef _Float16 f16x4 __attribute__((ext_vector_type(4)));
typedef _Float16 f16x8 __attribute__((ext_vector_type(8)));
typedef float f32x4 __attribute__((ext_vector_type(4)));

#define LRELU_SLOPE 0.2f

#define GLL16(g, l)                                                          \
  __builtin_amdgcn_global_load_lds(                                          \
      (const __attribute__((address_space(1))) void*)(g),                    \
      (__attribute__((address_space(3))) void*)(l), 16, 0, 0)

// ---------------- prep: x (f32) -> x_h (f16), padded rows zeroed ----------------
__global__ __launch_bounds__(256) void k_prep_xh(const float* __restrict__ x,
                                                 f16* __restrict__ xh,
                                                 int nvalid, int npad) {
  int total = npad * 192;
  for (int idx = blockIdx.x * blockDim.x + threadIdx.x; idx < total;
       idx += gridDim.x * blockDim.x) {
    int row = idx / 192;
    f16x4 o;
    if (row < nvalid) {
      const float4 v = *(const float4*)(x + (size_t)idx * 4);
      o[0] = (f16)v.x; o[1] = (f16)v.y; o[2] = (f16)v.z; o[3] = (f16)v.w;
    } else {
      o[0] = (f16)0.f; o[1] = (f16)0.f; o[2] = (f16)0.f; o[3] = (f16)0.f;
    }
    *(f16x4*)(xh + (size_t)idx * 4) = o;
  }
}

// ---------------- both W [768][768] f32 -> Wt [n][k] f16, one launch ----------------
__global__ __launch_bounds__(256) void k_transpose_w2(const float* __restrict__ W1,
                                                      const float* __restrict__ W2,
                                                      f16* __restrict__ Wt1,
                                                      f16* __restrict__ Wt2) {
  const float* W = blockIdx.z ? W2 : W1;
  f16* Wt = blockIdx.z ? Wt2 : Wt1;
  __shared__ float tile[32][33];
  int bn = blockIdx.x * 32;
  int bk = blockIdx.y * 32;
  int tx = threadIdx.x & 31, ty = threadIdx.x >> 5;
  #pragma unroll
  for (int r = ty; r < 32; r += 8)
    tile[r][tx] = W[(size_t)(bk + r) * 768 + bn + tx];
  __syncthreads();
  #pragma unroll
  for (int r = ty; r < 32; r += 8)
    Wt[(size_t)(bn + r) * 768 + bk + tx] = (f16)tile[tx][r];
}

// ---------------- CSR build ----------------
__global__ void k_hist(const int* __restrict__ dst, int E, int* __restrict__ counts) {
  for (int e = blockIdx.x * blockDim.x + threadIdx.x; e < E;
       e += gridDim.x * blockDim.x) atomicAdd(&counts[dst[e]], 1);
}

__global__ __launch_bounds__(1024) void k_scan_block(const int* __restrict__ counts,
                                                     int* __restrict__ starts,
                                                     int* __restrict__ cursor, int n) {
  const int t = threadIdx.x;
  const int nthr = 1024;
  const int chunk = (n + nthr - 1) / nthr;
  const int base = t * chunk;
  int tsum = 0;
  for (int i = 0; i < chunk; i++) {
    int idx = base + i;
    if (idx < n) tsum += counts[idx];
  }
  int lane = t & 63, wv = t >> 6;
  int s = tsum;
  #pragma unroll
  for (int off = 1; off < 64; off <<= 1) {
    int tmp = __shfl_up(s, off);
    if (lane >= off) s += tmp;
  }
  __shared__ int wsum[16];
  if (lane == 63) wsum[wv] = s;
  __syncthreads();
  int woff = 0;
  for (int w = 0; w < wv; w++) woff += wsum[w];
  int run = woff + s - tsum;
  for (int i = 0; i < chunk; i++) {
    int idx = base + i;
    if (idx < n) {
      starts[idx] = run;
      cursor[idx] = run;
      run += counts[idx];
    }
  }
  if (t == nthr - 1) starts[n] = run;
}

__global__ void k_fill(const int* __restrict__ src, const int* __restrict__ dst, int E,
                       int* __restrict__ cursor, int* __restrict__ src_sorted,
                       int* __restrict__ dst_sorted) {
  for (int e = blockIdx.x * blockDim.x + threadIdx.x; e < E;
       e += gridDim.x * blockDim.x) {
    int slot = atomicAdd(&cursor[dst[e]], 1);
    src_sorted[slot] = src[e];
    dst_sorted[slot] = dst[e];
  }
}

// ---------------- fp16 MFMA GEMM, BK=64, global_load_lds, slice-major C ----------
__global__ __launch_bounds__(256) void k_gemm_f16(const f16* __restrict__ A,
                                                  const f16* __restrict__ Bt,
                                                  f16* __restrict__ C, int Mvalid,
                                                  int SS) {
  __shared__ __align__(16) f16 As[8192];
  __shared__ __align__(16) f16 Bs[8192];
  const int K = 768;
  const int tid = threadIdx.x;
  const int bm = blockIdx.x * 128;
  const int bn = blockIdx.y * 128;
  const int lane = tid & 63;
  const int wave = tid >> 6;
  const int wr = (wave >> 1) * 64;
  const int wc = (wave & 1) * 64;

  size_t goffA[4], goffB[4];
  #pragma unroll
  for (int p = 0; p < 4; p++) {
    const int cell = p * 256 + tid;
    const int row = cell >> 3;
    const int cl = (cell & 7) ^ (row & 7);
    goffA[p] = (size_t)(bm + row) * K + cl * 8;
    goffB[p] = (size_t)(bn + row) * K + cl * 8;
  }

  f32x4 acc[4][4];
  const f32x4 vzero = {0.f, 0.f, 0.f, 0.f};
  #pragma unroll
  for (int i = 0; i < 4; i++)
    #pragma unroll
    for (int j = 0; j < 4; j++) acc[i][j] = vzero;

  const int fr = lane & 15;
  const int fq = lane >> 4;

  for (int k0 = 0; k0 < K; k0 += 64) {
    #pragma unroll
    for (int p = 0; p < 4; p++) GLL16(A + goffA[p] + k0, As + p * 2048 + wave * 512);
    #pragma unroll
    for (int p = 0; p < 4; p++) GLL16(Bt + goffB[p] + k0, Bs + p * 2048 + wave * 512);
    __syncthreads();
    #pragma unroll
    for (int ks = 0; ks < 2; ks++) {
      f16x8 af[4], bf[4];
      #pragma unroll
      for (int i = 0; i < 4; i++) {
        const int r = wr + i * 16 + fr;
        const int phys = (ks * 4 + fq) ^ (r & 7);
        af[i] = *(const f16x8*)(&As[r * 64 + phys * 8]);
      }
      #pragma unroll
      for (int j = 0; j < 4; j++) {
        const int r = wc + j * 16 + fr;
        const int phys = (ks * 4 + fq) ^ (r & 7);
        bf[j] = *(const f16x8*)(&Bs[r * 64 + phys * 8]);
      }
      #pragma unroll
      for (int i = 0; i < 4; i++)
        #pragma unroll
        for (int j = 0; j < 4; j++)
          acc[i][j] = __builtin_amdgcn_mfma_f32_16x16x32_f16(af[i], bf[j], acc[i][j], 0, 0, 0);
    }
    __syncthreads();
  }

  #pragma unroll
  for (int i = 0; i < 4; i++) {
    #pragma unroll
    for (int j = 0; j < 4; j++) {
      const int col = bn + wc + j * 16 + fr;
      const int cs = col / 96;
      const int cw = col - cs * 96;
      f16* cp = C + (size_t)cs * SS + cw;
      #pragma unroll
      for (int r = 0; r < 4; r++) {
        const int row = bm + wr + i * 16 + fq * 4 + r;
        if (row < Mvalid) cp[(size_t)row * 96] = (f16)acc[i][j][r];
      }
    }
  }
}

// ---------------- attention logits from slice-major h ----------------
template <int H>
__global__ __launch_bounds__(256) void k_al(const f16* __restrict__ hs,
                                            const float* __restrict__ a_src,
                                            const float* __restrict__ a_dst,
                                            float* __restrict__ als,
                                            float* __restrict__ ald, int N, int SS) {
  int node = blockIdx.x * 4 + (threadIdx.x >> 6);
  int lane = threadIdx.x & 63;
  if (node >= N) return;
  const int sl = lane >> 3, wl = lane & 7;
  const f16* hp = hs + (size_t)sl * SS + (size_t)node * 96 + wl * 12;
  float ss = 0.f, sd = 0.f;
  const int cbase = sl * 96 + wl * 12;
  #pragma unroll
  for (int q = 0; q < 3; q++) {
    f16x4 hv = *(const f16x4*)(hp + q * 4);
    #pragma unroll
    for (int j = 0; j < 4; j++) {
      int c = cbase + q * 4 + j;
      float v = (float)hv[j];
      ss += v * a_src[c];
      sd += v * a_dst[c];
    }
  }
  const int red = (H == 8) ? 8 : 64;
  #pragma unroll
  for (int off = 1; off < red; off <<= 1) {
    ss += __shfl_xor(ss, off);
    sd += __shfl_xor(sd, off);
  }
  if (H == 8) {
    if ((lane & 7) == 0) {
      als[(size_t)node * 8 + sl] = ss;
      ald[(size_t)node * 8 + sl] = sd;
    }
  } else {
    if (lane == 0) { als[node] = ss; ald[node] = sd; }
  }
}

// ---------------- edge-parallel exp(leaky_relu(logit)) on SORTED edges ----------
template <int H>
__global__ __launch_bounds__(256) void k_alpha(const float* __restrict__ als,
                                               const float* __restrict__ ald,
                                               const int* __restrict__ srcs,
                                               const int* __restrict__ dsts,
                                               float* __restrict__ ex, int E) {
  const int e = blockIdx.x * 256 + threadIdx.x;
  if (e >= E) return;
  const int s = srcs[e], d = dsts[e];
  #pragma unroll
  for (int h = 0; h < H; h++) {
    float v = als[(size_t)s * H + h] + ald[(size_t)d * H + h];
    v = v > 0.f ? v : LRELU_SLOPE * v;
    ex[(size_t)h * E + e] = __expf(v);
  }
}

// ---------------- per-node zinv from ex planes via CSR ----------------
template <int H>
__global__ __launch_bounds__(256) void k_z(const float* __restrict__ ex,
                                           const int* __restrict__ starts,
                                           float* __restrict__ zinv, int N, int E) {
  int node = blockIdx.x * 4 + (threadIdx.x >> 6);
  int lane = threadIdx.x & 63;
  if (node >= N) return;
  const int start = starts[node];
  const int deg = starts[node + 1] - start;
  float z = 0.f;
  if (H == 8) {
    const int h = lane & 7;
    const float* exh = ex + (size_t)h * E + start;
    for (int j = lane >> 3; j < deg; j += 8) z += exh[j];
    #pragma unroll
    for (int off = 8; off < 64; off <<= 1) z += __shfl_xor(z, off);
    if (lane < 8) zinv[(size_t)node * 8 + h] = 1.f / (z + 1e-16f);
  } else {
    const float* exh = ex + start;
    for (int j = lane; j < deg; j += 64) z += exh[j];
    #pragma unroll
    for (int off = 1; off < 64; off <<= 1) z += __shfl_xor(z, off);
    if (lane == 0) zinv[node] = 1.f / (z + 1e-16f);
  }
}

// ---------------- slice-blocked SpMM v2: register-only, batched nodes -----------
// block = (slice s, 128-node chunk); bid = g*8+s pins slice->XCD (verified 3x:
// per-XCD working set = 3.84MB slice -> L2). 192 thr = 8 node-slots x 24 ch-lanes;
// each slot processes nodes serially, acc in registers; no LDS, no atomics.
template <int H, bool FINAL>
__global__ __launch_bounds__(192) void k_spmm2(
    const f16* __restrict__ hs, const float* __restrict__ ex,
    const float* __restrict__ zinv, const int* __restrict__ starts,
    const int* __restrict__ srcs, const float* __restrict__ bias,
    void* __restrict__ outv, int N, int SS, int E) {
  const int s = blockIdx.x & 7;
  const int g = blockIdx.x >> 3;
  const int n0 = g * 128;
  const int t = threadIdx.x;
  const int slot = t / 24;     // 0..7
  const int c = t - slot * 24; // 0..23
  const int head = (H == 8) ? s : 0;
  const f16* hsl = hs + (size_t)s * SS;
  const float* exh = ex + (size_t)head * E;
  const float4 bv = *(const float4*)(bias + s * 96 + c * 4);
  const int nend = min(n0 + 128, N);

  for (int n = n0 + slot; n < nend; n += 8) {
    const int e0 = starts[n];
    const int e1 = starts[n + 1];
    float4 acc = {0.f, 0.f, 0.f, 0.f};
    for (int i = e0; i < e1; i++) {
      const float a = exh[i];
      const int sv = srcs[i];
      const f16x4 hv = *(const f16x4*)(hsl + (size_t)sv * 96 + c * 4);
      acc.x += a * (float)hv[0];
      acc.y += a * (float)hv[1];
      acc.z += a * (float)hv[2];
      acc.w += a * (float)hv[3];
    }
    const float zi = zinv[(size_t)n * H + head];
    float v0 = acc.x * zi + bv.x;
    float v1 = acc.y * zi + bv.y;
    float v2 = acc.z * zi + bv.z;
    float v3 = acc.w * zi + bv.w;
    if (FINAL) {
      float4 o = {v0, v1, v2, v3};
      *(float4*)((float*)outv + (size_t)n * 768 + s * 96 + c * 4) = o;
    } else {
      v0 = v0 > 0.f ? v0 : expm1f(v0);
      v1 = v1 > 0.f ? v1 : expm1f(v1);
      v2 = v2 > 0.f ? v2 : expm1f(v2);
      v3 = v3 > 0.f ? v3 : expm1f(v3);
      f16x4 o;
      o[0] = (f16)v0; o[1] = (f16)v1; o[2] = (f16)v2; o[3] = (f16)v3;
      *(f16x4*)((f16*)outv + (size_t)n * 768 + s * 96 + c * 4) = o;
    }
  }
}

// ---------------- launcher ----------------
extern "C" void kernel_launch(void* const* d_in, const int* in_sizes, int n_in,
                              void* d_out, int out_size, void* d_ws, size_t ws_size,
                              hipStream_t stream) {
  const float* x   = (const float*)d_in[0];
  const int*   ei  = (const int*)d_in[1];
  const float* W1  = (const float*)d_in[2];
  const float* as1 = (const float*)d_in[3];
  const float* ad1 = (const float*)d_in[4];
  const float* b1  = (const float*)d_in[5];
  const float* W2  = (const float*)d_in[6];
  const float* as2 = (const float*)d_in[7];
  const float* ad2 = (const float*)d_in[8];
  const float* b2  = (const float*)d_in[9];

  const int N = in_sizes[0] / 768;
  const int E = in_sizes[1] / 2;
  const int Mpad = (N + 127) & ~127;
  const int SS = Mpad * 96;
  const int* srcp = ei;
  const int* dstp = ei + E;

  char* p = (char*)d_ws;
  auto alloc = [&](size_t b) { char* r = p; p += (b + 255) & ~(size_t)255; return r; };
  f16*   bufX   = (f16*)alloc((size_t)Mpad * 768 * sizeof(f16));  // x_h, then out1
  f16*   bufH   = (f16*)alloc((size_t)Mpad * 768 * sizeof(f16));  // h slice-major
  f16*   Wt1    = (f16*)alloc((size_t)768 * 768 * sizeof(f16));
  f16*   Wt2    = (f16*)alloc((size_t)768 * 768 * sizeof(f16));
  float* ex     = (float*)alloc((size_t)8 * E * sizeof(float));
  float* als1   = (float*)alloc((size_t)N * 8 * sizeof(float));
  float* ald1   = (float*)alloc((size_t)N * 8 * sizeof(float));
  float* zinv1  = (float*)alloc((size_t)N * 8 * sizeof(float));
  float* als2   = (float*)alloc((size_t)N * sizeof(float));
  float* ald2   = (float*)alloc((size_t)N * sizeof(float));
  float* zinv2  = (float*)alloc((size_t)N * sizeof(float));
  int*   counts = (int*)alloc((size_t)N * sizeof(int));
  int*   starts = (int*)alloc(((size_t)N + 1) * sizeof(int));
  int*   cursor = (int*)alloc((size_t)N * sizeof(int));
  int*   srcs   = (int*)alloc((size_t)E * sizeof(int));
  int*   dsts   = (int*)alloc((size_t)E * sizeof(int));

  // CSR build
  hipMemsetAsync(counts, 0, (size_t)N * sizeof(int), stream);
  k_hist<<<dim3(512), dim3(256), 0, stream>>>(dstp, E, counts);
  k_scan_block<<<dim3(1), dim3(1024), 0, stream>>>(counts, starts, cursor, N);
  k_fill<<<dim3(512), dim3(256), 0, stream>>>(srcp, dstp, E, cursor, srcs, dsts);

  // prep
  k_prep_xh<<<dim3(1024), dim3(256), 0, stream>>>(x, bufX, N, Mpad);
  k_transpose_w2<<<dim3(24, 24, 2), dim3(256), 0, stream>>>(W1, W2, Wt1, Wt2);

  const int eb = (E + 255) / 256;
  const int ngroups = (N + 127) / 128;

  // layer 1
  k_gemm_f16<<<dim3(Mpad / 128, 6), dim3(256), 0, stream>>>(bufX, Wt1, bufH, N, SS);
  k_al<8><<<dim3((N + 3) / 4), dim3(256), 0, stream>>>(bufH, as1, ad1, als1, ald1, N, SS);
  k_alpha<8><<<dim3(eb), dim3(256), 0, stream>>>(als1, ald1, srcs, dsts, ex, E);
  k_z<8><<<dim3((N + 3) / 4), dim3(256), 0, stream>>>(ex, starts, zinv1, N, E);
  k_spmm2<8, false><<<dim3(ngroups * 8), dim3(192), 0, stream>>>(
      bufH, ex, zinv1, starts, srcs, b1, bufX, N, SS, E);

  // layer 2 (bufX pad rows still hold k_prep_xh zeros)
  k_gemm_f16<<<dim3(Mpad / 128, 6), dim3(256), 0, stream>>>(bufX, Wt2, bufH, N, SS);
  k_al<1><<<dim3((N + 3) / 4), dim3(256), 0, stream>>>(bufH, as2, ad2, als2, ald2, N, SS);
  k_alpha<1><<<dim3(eb), dim3(256), 0, stream>>>(als2, ald2, srcs, dsts, ex, E);
  k_z<1><<<dim3((N + 3) / 4), dim3(256), 0, stream>>>(ex, starts, zinv2, N, E);
  k_spmm2<1, true><<<dim3(ngroups * 8), dim3(192), 0, stream>>>(
      bufH, ex, zinv2, starts, srcs, b2, d_out, N, SS, E);
}

// Round 9
// 379.774 us; speedup vs baseline: 7.6236x; 1.6090x over previous
//
#include <hip/hip_runtime.h>
#include <cstdint>
#include <cstddef>

typedef _Float16 f16;
typedef _Float16 f16x4 __attribute__((ext_vector_type(4)));
typedef _Float16 f16x8 __attribute__((ext_vector_type(8)));
typedef float f32x4 __attribute__((ext_vector_type(4)));

#define LRELU_SLOPE 0.2f

#define GLL16(g, l)                                                          \
  __builtin_amdgcn_global_load_lds(                                          \
      (const __attribute__((address_space(1))) void*)(g),                    \
      (__attribute__((address_space(3))) void*)(l), 16, 0, 0)

// ---------------- prep: x (f32) -> x_h (f16), padded rows zeroed ----------------
__global__ __launch_bounds__(256) void k_prep_xh(const float* __restrict__ x,
                                                 f16* __restrict__ xh,
                                                 int nvalid, int npad) {
  int total = npad * 192;
  for (int idx = blockIdx.x * blockDim.x + threadIdx.x; idx < total;
       idx += gridDim.x * blockDim.x) {
    int row = idx / 192;
    f16x4 o;
    if (row < nvalid) {
      const float4 v = *(const float4*)(x + (size_t)idx * 4);
      o[0] = (f16)v.x; o[1] = (f16)v.y; o[2] = (f16)v.z; o[3] = (f16)v.w;
    } else {
      o[0] = (f16)0.f; o[1] = (f16)0.f; o[2] = (f16)0.f; o[3] = (f16)0.f;
    }
    *(f16x4*)(xh + (size_t)idx * 4) = o;
  }
}

// ---------------- both W [768][768] f32 -> Wt [n][k] f16, one launch ----------------
__global__ __launch_bounds__(256) void k_transpose_w2(const float* __restrict__ W1,
                                                      const float* __restrict__ W2,
                                                      f16* __restrict__ Wt1,
                                                      f16* __restrict__ Wt2) {
  const float* W = blockIdx.z ? W2 : W1;
  f16* Wt = blockIdx.z ? Wt2 : Wt1;
  __shared__ float tile[32][33];
  int bn = blockIdx.x * 32;
  int bk = blockIdx.y * 32;
  int tx = threadIdx.x & 31, ty = threadIdx.x >> 5;
  #pragma unroll
  for (int r = ty; r < 32; r += 8)
    tile[r][tx] = W[(size_t)(bk + r) * 768 + bn + tx];
  __syncthreads();
  #pragma unroll
  for (int r = ty; r < 32; r += 8)
    Wt[(size_t)(bn + r) * 768 + bk + tx] = (f16)tile[tx][r];
}

// ---------------- CSR build ----------------
__global__ void k_hist(const int* __restrict__ dst, int E, int* __restrict__ counts) {
  for (int e = blockIdx.x * blockDim.x + threadIdx.x; e < E;
       e += gridDim.x * blockDim.x) atomicAdd(&counts[dst[e]], 1);
}

__global__ __launch_bounds__(1024) void k_scan_block(const int* __restrict__ counts,
                                                     int* __restrict__ starts,
                                                     int* __restrict__ cursor, int n) {
  const int t = threadIdx.x;
  const int nthr = 1024;
  const int chunk = (n + nthr - 1) / nthr;
  const int base = t * chunk;
  int tsum = 0;
  for (int i = 0; i < chunk; i++) {
    int idx = base + i;
    if (idx < n) tsum += counts[idx];
  }
  int lane = t & 63, wv = t >> 6;
  int s = tsum;
  #pragma unroll
  for (int off = 1; off < 64; off <<= 1) {
    int tmp = __shfl_up(s, off);
    if (lane >= off) s += tmp;
  }
  __shared__ int wsum[16];
  if (lane == 63) wsum[wv] = s;
  __syncthreads();
  int woff = 0;
  for (int w = 0; w < wv; w++) woff += wsum[w];
  int run = woff + s - tsum;
  for (int i = 0; i < chunk; i++) {
    int idx = base + i;
    if (idx < n) {
      starts[idx] = run;
      cursor[idx] = run;
      run += counts[idx];
    }
  }
  if (t == nthr - 1) starts[n] = run;
}

__global__ void k_fill(const int* __restrict__ src, const int* __restrict__ dst, int E,
                       int* __restrict__ cursor, int* __restrict__ src_sorted) {
  for (int e = blockIdx.x * blockDim.x + threadIdx.x; e < E;
       e += gridDim.x * blockDim.x) {
    int slot = atomicAdd(&cursor[dst[e]], 1);
    src_sorted[slot] = src[e];
  }
}

// ---------------- fp16 MFMA GEMM, BK=64, global_load_lds + FUSED attention logits
// Epilogue: per lane, dot its 16 C-values with a_src/a_dst (flat idx = col for
// both H=8 (8x96) and H=1 (1x768)), shfl-reduce over 16 fr-lanes, atomicAdd
// per (row, head). als/ald must be pre-zeroed.
template <int H>
__global__ __launch_bounds__(256) void k_gemm_f16(const f16* __restrict__ A,
                                                  const f16* __restrict__ Bt,
                                                  f16* __restrict__ C,
                                                  const float* __restrict__ a_src,
                                                  const float* __restrict__ a_dst,
                                                  float* __restrict__ als,
                                                  float* __restrict__ ald,
                                                  int Mvalid) {
  __shared__ __align__(16) f16 As[8192];
  __shared__ __align__(16) f16 Bs[8192];
  const int K = 768;
  const int tid = threadIdx.x;
  const int bm = blockIdx.x * 128;
  const int bn = blockIdx.y * 128;
  const int lane = tid & 63;
  const int wave = tid >> 6;
  const int wr = (wave >> 1) * 64;
  const int wc = (wave & 1) * 64;

  size_t goffA[4], goffB[4];
  #pragma unroll
  for (int p = 0; p < 4; p++) {
    const int cell = p * 256 + tid;
    const int row = cell >> 3;
    const int cl = (cell & 7) ^ (row & 7);
    goffA[p] = (size_t)(bm + row) * K + cl * 8;
    goffB[p] = (size_t)(bn + row) * K + cl * 8;
  }

  f32x4 acc[4][4];
  const f32x4 vzero = {0.f, 0.f, 0.f, 0.f};
  #pragma unroll
  for (int i = 0; i < 4; i++)
    #pragma unroll
    for (int j = 0; j < 4; j++) acc[i][j] = vzero;

  const int fr = lane & 15;
  const int fq = lane >> 4;

  for (int k0 = 0; k0 < K; k0 += 64) {
    #pragma unroll
    for (int p = 0; p < 4; p++) GLL16(A + goffA[p] + k0, As + p * 2048 + wave * 512);
    #pragma unroll
    for (int p = 0; p < 4; p++) GLL16(Bt + goffB[p] + k0, Bs + p * 2048 + wave * 512);
    __syncthreads();
    #pragma unroll
    for (int ks = 0; ks < 2; ks++) {
      f16x8 af[4], bf[4];
      #pragma unroll
      for (int i = 0; i < 4; i++) {
        const int r = wr + i * 16 + fr;
        const int phys = (ks * 4 + fq) ^ (r & 7);
        af[i] = *(const f16x8*)(&As[r * 64 + phys * 8]);
      }
      #pragma unroll
      for (int j = 0; j < 4; j++) {
        const int r = wc + j * 16 + fr;
        const int phys = (ks * 4 + fq) ^ (r & 7);
        bf[j] = *(const f16x8*)(&Bs[r * 64 + phys * 8]);
      }
      #pragma unroll
      for (int i = 0; i < 4; i++)
        #pragma unroll
        for (int j = 0; j < 4; j++)
          acc[i][j] = __builtin_amdgcn_mfma_f32_16x16x32_f16(af[i], bf[j], acc[i][j], 0, 0, 0);
    }
    __syncthreads();
  }

  // C store
  #pragma unroll
  for (int i = 0; i < 4; i++) {
    #pragma unroll
    for (int j = 0; j < 4; j++) {
      const int col = bn + wc + j * 16 + fr;
      #pragma unroll
      for (int r = 0; r < 4; r++) {
        const int row = bm + wr + i * 16 + fq * 4 + r;
        if (row < Mvalid) C[(size_t)row * 768 + col] = (f16)acc[i][j][r];
      }
    }
  }

  // fused attention-logit partials
  const int hA = (H == 8) ? ((bn + wc) / 96) : 0;
  const int hB = (H == 8) ? ((bn + wc + 63) / 96) : 0;
  #pragma unroll
  for (int i = 0; i < 4; i++) {
    #pragma unroll
    for (int r = 0; r < 4; r++) {
      const int row = bm + wr + i * 16 + fq * 4 + r;
      float sA = 0.f, dA = 0.f, sB = 0.f, dB = 0.f;
      #pragma unroll
      for (int j = 0; j < 4; j++) {
        const int col = bn + wc + j * 16 + fr;
        const float v = acc[i][j][r];
        const float as = a_src[col], ad = a_dst[col];
        if (H == 8 && (col / 96) != hA) { sB += v * as; dB += v * ad; }
        else { sA += v * as; dA += v * ad; }
      }
      #pragma unroll
      for (int off = 1; off < 16; off <<= 1) {
        sA += __shfl_xor(sA, off);
        dA += __shfl_xor(dA, off);
        if (H == 8 && hB != hA) {
          sB += __shfl_xor(sB, off);
          dB += __shfl_xor(dB, off);
        }
      }
      if (fr == 0 && row < Mvalid) {
        atomicAdd(&als[(size_t)row * H + hA], sA);
        atomicAdd(&ald[(size_t)row * H + hA], dA);
        if (H == 8 && hB != hA) {
          atomicAdd(&als[(size_t)row * H + hB], sB);
          atomicAdd(&ald[(size_t)row * H + hB], dB);
        }
      }
    }
  }
}

// ---------------- fused segment softmax + aggregation + bias (+ELU) ----------------
// proven structure (73.5us): 192 threads, coalesced full-row gather, LDS alphas.
// nbase: grid split for profile visibility. Phase-B unrolled x4 (latency probe).
template <int H, bool FINAL>
__global__ __launch_bounds__(192) void k_aggregate(
    const f16* __restrict__ h, const float* __restrict__ als,
    const float* __restrict__ ald, const int* __restrict__ starts,
    const int* __restrict__ src_sorted, const float* __restrict__ bias,
    void* __restrict__ outv, int nvalid, int nbase) {
  const int n = nbase + blockIdx.x;
  const int t = threadIdx.x;
  if (n >= nvalid) return;
  __shared__ float s_ex[256 * H];
  __shared__ int s_src[256];
  __shared__ float s_zp[3][H];
  const int start = starts[n];
  const int deg = starts[n + 1] - start;
  const int lane = t & 63, wv = t >> 6;
  const int hA = (H == 8) ? (t & 7) : 0;
  const int myh = (H == 8) ? (t / 24) : 0;
  const float ald_A = ald[(size_t)n * H + hA];

  float zpart = 0.f;
  float4 acc = {0.f, 0.f, 0.f, 0.f};

  for (int cb = 0; cb < deg; cb += 256) {
    const int cnt = min(256, deg - cb);
    for (int idx = t; idx < cnt * H; idx += 192) {
      const int e = (H == 8) ? (idx >> 3) : idx;
      const int s = src_sorted[start + cb + e];
      if (H == 1 || (idx & 7) == 0) s_src[e] = s;
      float v = als[(size_t)s * H + hA] + ald_A;
      v = v > 0.f ? v : LRELU_SLOPE * v;
      const float ex = __expf(v);
      s_ex[idx] = ex;
      zpart += ex;
    }
    __syncthreads();
    #pragma unroll 4
    for (int e = 0; e < cnt; e++) {
      const f16x4 hv = *(const f16x4*)(h + (size_t)s_src[e] * 768 + 4 * t);
      const float a = s_ex[e * H + myh];
      acc.x += a * (float)hv[0];
      acc.y += a * (float)hv[1];
      acc.z += a * (float)hv[2];
      acc.w += a * (float)hv[3];
    }
    __syncthreads();
  }

  if (H == 8) {
    #pragma unroll
    for (int off = 8; off < 64; off <<= 1) zpart += __shfl_xor(zpart, off);
    if (lane < 8) s_zp[wv][lane] = zpart;
  } else {
    #pragma unroll
    for (int off = 1; off < 64; off <<= 1) zpart += __shfl_xor(zpart, off);
    if (lane == 0) s_zp[wv][0] = zpart;
  }
  __syncthreads();
  const float z = s_zp[0][myh] + s_zp[1][myh] + s_zp[2][myh];
  const float inv = 1.f / (z + 1e-16f);

  const float4 bv = *(const float4*)(bias + 4 * t);
  float v0 = acc.x * inv + bv.x;
  float v1 = acc.y * inv + bv.y;
  float v2 = acc.z * inv + bv.z;
  float v3 = acc.w * inv + bv.w;
  if (!FINAL) {
    v0 = v0 > 0.f ? v0 : expm1f(v0);
    v1 = v1 > 0.f ? v1 : expm1f(v1);
    v2 = v2 > 0.f ? v2 : expm1f(v2);
    v3 = v3 > 0.f ? v3 : expm1f(v3);
    f16x4 o;
    o[0] = (f16)v0; o[1] = (f16)v1; o[2] = (f16)v2; o[3] = (f16)v3;
    *(f16x4*)((f16*)outv + (size_t)n * 768 + 4 * t) = o;
  } else {
    float4 o = {v0, v1, v2, v3};
    *(float4*)((float*)outv + (size_t)n * 768 + 4 * t) = o;
  }
}

// ---------------- launcher ----------------
extern "C" void kernel_launch(void* const* d_in, const int* in_sizes, int n_in,
                              void* d_out, int out_size, void* d_ws, size_t ws_size,
                              hipStream_t stream) {
  const float* x   = (const float*)d_in[0];
  const int*   ei  = (const int*)d_in[1];
  const float* W1  = (const float*)d_in[2];
  const float* as1 = (const float*)d_in[3];
  const float* ad1 = (const float*)d_in[4];
  const float* b1  = (const float*)d_in[5];
  const float* W2  = (const float*)d_in[6];
  const float* as2 = (const float*)d_in[7];
  const float* ad2 = (const float*)d_in[8];
  const float* b2  = (const float*)d_in[9];

  const int N = in_sizes[0] / 768;
  const int E = in_sizes[1] / 2;
  const int Mpad = (N + 127) & ~127;
  const int* srcp = ei;
  const int* dstp = ei + E;

  char* p = (char*)d_ws;
  auto alloc = [&](size_t b) { char* r = p; p += (b + 255) & ~(size_t)255; return r; };
  f16*   bufX   = (f16*)alloc((size_t)Mpad * 768 * sizeof(f16));  // x_h, then out1
  f16*   bufH   = (f16*)alloc((size_t)Mpad * 768 * sizeof(f16));  // h1, then h2
  f16*   Wt1    = (f16*)alloc((size_t)768 * 768 * sizeof(f16));
  f16*   Wt2    = (f16*)alloc((size_t)768 * 768 * sizeof(f16));
  float* als1   = (float*)alloc((size_t)N * 8 * sizeof(float));
  float* ald1   = (float*)alloc((size_t)N * 8 * sizeof(float));
  float* als2   = (float*)alloc((size_t)N * sizeof(float));
  float* ald2   = (float*)alloc((size_t)N * sizeof(float));
  int*   counts = (int*)alloc((size_t)N * sizeof(int));
  int*   starts = (int*)alloc(((size_t)N + 1) * sizeof(int));
  int*   cursor = (int*)alloc((size_t)N * sizeof(int));
  int*   srcs   = (int*)alloc((size_t)E * sizeof(int));

  // zero CSR counts + all logit accumulators (als1..ald2 are contiguous in ws)
  hipMemsetAsync(counts, 0, (size_t)N * sizeof(int), stream);
  hipMemsetAsync(als1, 0, (size_t)((char*)(ald2 + N) - (char*)als1), stream);

  // CSR build
  k_hist<<<dim3(512), dim3(256), 0, stream>>>(dstp, E, counts);
  k_scan_block<<<dim3(1), dim3(1024), 0, stream>>>(counts, starts, cursor, N);
  k_fill<<<dim3(512), dim3(256), 0, stream>>>(srcp, dstp, E, cursor, srcs);

  // prep
  k_prep_xh<<<dim3(1024), dim3(256), 0, stream>>>(x, bufX, N, Mpad);
  k_transpose_w2<<<dim3(24, 24, 2), dim3(256), 0, stream>>>(W1, W2, Wt1, Wt2);

  const int nh1 = (N + 1) / 2;
  const int nh2 = N - nh1;

  // layer 1 (al fused into GEMM epilogue)
  k_gemm_f16<8><<<dim3(Mpad / 128, 6), dim3(256), 0, stream>>>(
      bufX, Wt1, bufH, as1, ad1, als1, ald1, N);
  k_aggregate<8, false><<<dim3(nh1), dim3(192), 0, stream>>>(
      bufH, als1, ald1, starts, srcs, b1, bufX, N, 0);
  k_aggregate<8, false><<<dim3(nh2), dim3(192), 0, stream>>>(
      bufH, als1, ald1, starts, srcs, b1, bufX, N, nh1);

  // layer 2
  k_gemm_f16<1><<<dim3(Mpad / 128, 6), dim3(256), 0, stream>>>(
      bufX, Wt2, bufH, as2, ad2, als2, ald2, N);
  k_aggregate<1, true><<<dim3(nh1), dim3(192), 0, stream>>>(
      bufH, als2, ald2, starts, srcs, b2, d_out, N, 0);
  k_aggregate<1, true><<<dim3(nh2), dim3(192), 0, stream>>>(
      bufH, als2, ald2, starts, srcs, b2, d_out, N, nh1);
}

// Round 10
// 364.231 us; speedup vs baseline: 7.9489x; 1.0427x over previous
//
#include <hip/hip_runtime.h>
#include <cstdint>
#include <cstddef>

typedef _Float16 f16;
typedef _Float16 f16x2 __attribute__((ext_vector_type(2)));
typedef _Float16 f16x4 __attribute__((ext_vector_type(4)));
typedef _Float16 f16x8 __attribute__((ext_vector_type(8)));
typedef float f32x4 __attribute__((ext_vector_type(4)));

#define LRELU_SLOPE 0.2f

#define GLL16(g, l)                                                          \
  __builtin_amdgcn_global_load_lds(                                          \
      (const __attribute__((address_space(1))) void*)(g),                    \
      (__attribute__((address_space(3))) void*)(l), 16, 0, 0)

// ---------------- prep: x (f32) -> x_h (f16), padded rows zeroed ----------------
__global__ __launch_bounds__(256) void k_prep_xh(const float* __restrict__ x,
                                                 f16* __restrict__ xh,
                                                 int nvalid, int npad) {
  int total = npad * 192;
  for (int idx = blockIdx.x * blockDim.x + threadIdx.x; idx < total;
       idx += gridDim.x * blockDim.x) {
    int row = idx / 192;
    f16x4 o;
    if (row < nvalid) {
      const float4 v = *(const float4*)(x + (size_t)idx * 4);
      o[0] = (f16)v.x; o[1] = (f16)v.y; o[2] = (f16)v.z; o[3] = (f16)v.w;
    } else {
      o[0] = (f16)0.f; o[1] = (f16)0.f; o[2] = (f16)0.f; o[3] = (f16)0.f;
    }
    *(f16x4*)(xh + (size_t)idx * 4) = o;
  }
}

// ---------------- both W [768][768] f32 -> Wt [n][k] f16, one launch ----------------
__global__ __launch_bounds__(256) void k_transpose_w2(const float* __restrict__ W1,
                                                      const float* __restrict__ W2,
                                                      f16* __restrict__ Wt1,
                                                      f16* __restrict__ Wt2) {
  const float* W = blockIdx.z ? W2 : W1;
  f16* Wt = blockIdx.z ? Wt2 : Wt1;
  __shared__ float tile[32][33];
  int bn = blockIdx.x * 32;
  int bk = blockIdx.y * 32;
  int tx = threadIdx.x & 31, ty = threadIdx.x >> 5;
  #pragma unroll
  for (int r = ty; r < 32; r += 8)
    tile[r][tx] = W[(size_t)(bk + r) * 768 + bn + tx];
  __syncthreads();
  #pragma unroll
  for (int r = ty; r < 32; r += 8)
    Wt[(size_t)(bn + r) * 768 + bk + tx] = (f16)tile[tx][r];
}

// ---------------- CSR build ----------------
__global__ void k_hist(const int* __restrict__ dst, int E, int* __restrict__ counts) {
  for (int e = blockIdx.x * blockDim.x + threadIdx.x; e < E;
       e += gridDim.x * blockDim.x) atomicAdd(&counts[dst[e]], 1);
}

__global__ __launch_bounds__(1024) void k_scan_block(const int* __restrict__ counts,
                                                     int* __restrict__ starts,
                                                     int* __restrict__ cursor, int n) {
  const int t = threadIdx.x;
  const int nthr = 1024;
  const int chunk = (n + nthr - 1) / nthr;
  const int base = t * chunk;
  int tsum = 0;
  for (int i = 0; i < chunk; i++) {
    int idx = base + i;
    if (idx < n) tsum += counts[idx];
  }
  int lane = t & 63, wv = t >> 6;
  int s = tsum;
  #pragma unroll
  for (int off = 1; off < 64; off <<= 1) {
    int tmp = __shfl_up(s, off);
    if (lane >= off) s += tmp;
  }
  __shared__ int wsum[16];
  if (lane == 63) wsum[wv] = s;
  __syncthreads();
  int woff = 0;
  for (int w = 0; w < wv; w++) woff += wsum[w];
  int run = woff + s - tsum;
  for (int i = 0; i < chunk; i++) {
    int idx = base + i;
    if (idx < n) {
      starts[idx] = run;
      cursor[idx] = run;
      run += counts[idx];
    }
  }
  if (t == nthr - 1) starts[n] = run;
}

__global__ void k_fill(const int* __restrict__ src, const int* __restrict__ dst, int E,
                       int* __restrict__ cursor, int* __restrict__ src_sorted,
                       int* __restrict__ dst_sorted) {
  for (int e = blockIdx.x * blockDim.x + threadIdx.x; e < E;
       e += gridDim.x * blockDim.x) {
    int slot = atomicAdd(&cursor[dst[e]], 1);
    src_sorted[slot] = src[e];
    dst_sorted[slot] = dst[e];
  }
}

// ---------------- fp16 MFMA GEMM, BK=64, global_load_lds (round-6 proven) --------
__global__ __launch_bounds__(256) void k_gemm_f16(const f16* __restrict__ A,
                                                  const f16* __restrict__ Bt,
                                                  f16* __restrict__ C, int Mvalid) {
  __shared__ __align__(16) f16 As[8192];
  __shared__ __align__(16) f16 Bs[8192];
  const int K = 768;
  const int tid = threadIdx.x;
  const int bm = blockIdx.x * 128;
  const int bn = blockIdx.y * 128;
  const int lane = tid & 63;
  const int wave = tid >> 6;
  const int wr = (wave >> 1) * 64;
  const int wc = (wave & 1) * 64;

  size_t goffA[4], goffB[4];
  #pragma unroll
  for (int p = 0; p < 4; p++) {
    const int cell = p * 256 + tid;
    const int row = cell >> 3;
    const int cl = (cell & 7) ^ (row & 7);
    goffA[p] = (size_t)(bm + row) * K + cl * 8;
    goffB[p] = (size_t)(bn + row) * K + cl * 8;
  }

  f32x4 acc[4][4];
  const f32x4 vzero = {0.f, 0.f, 0.f, 0.f};
  #pragma unroll
  for (int i = 0; i < 4; i++)
    #pragma unroll
    for (int j = 0; j < 4; j++) acc[i][j] = vzero;

  const int fr = lane & 15;
  const int fq = lane >> 4;

  for (int k0 = 0; k0 < K; k0 += 64) {
    #pragma unroll
    for (int p = 0; p < 4; p++) GLL16(A + goffA[p] + k0, As + p * 2048 + wave * 512);
    #pragma unroll
    for (int p = 0; p < 4; p++) GLL16(Bt + goffB[p] + k0, Bs + p * 2048 + wave * 512);
    __syncthreads();
    #pragma unroll
    for (int ks = 0; ks < 2; ks++) {
      f16x8 af[4], bf[4];
      #pragma unroll
      for (int i = 0; i < 4; i++) {
        const int r = wr + i * 16 + fr;
        const int phys = (ks * 4 + fq) ^ (r & 7);
        af[i] = *(const f16x8*)(&As[r * 64 + phys * 8]);
      }
      #pragma unroll
      for (int j = 0; j < 4; j++) {
        const int r = wc + j * 16 + fr;
        const int phys = (ks * 4 + fq) ^ (r & 7);
        bf[j] = *(const f16x8*)(&Bs[r * 64 + phys * 8]);
      }
      #pragma unroll
      for (int i = 0; i < 4; i++)
        #pragma unroll
        for (int j = 0; j < 4; j++)
          acc[i][j] = __builtin_amdgcn_mfma_f32_16x16x32_f16(af[i], bf[j], acc[i][j], 0, 0, 0);
    }
    __syncthreads();
  }

  #pragma unroll
  for (int i = 0; i < 4; i++) {
    #pragma unroll
    for (int j = 0; j < 4; j++) {
      const int col = bn + wc + j * 16 + fr;
      #pragma unroll
      for (int r = 0; r < 4; r++) {
        const int row = bm + wr + i * 16 + fq * 4 + r;
        if (row < Mvalid) C[(size_t)row * 768 + col] = (f16)acc[i][j][r];
      }
    }
  }
}

// ---------------- attention logits: al[n][h] = sum_c h[n][h*C+c]*a[h][c] ----------
template <int H>
__global__ __launch_bounds__(256) void k_al(const f16* __restrict__ h,
                                            const float* __restrict__ a_src,
                                            const float* __restrict__ a_dst,
                                            float* __restrict__ als,
                                            float* __restrict__ ald, int N) {
  int node = blockIdx.x * 4 + (threadIdx.x >> 6);
  int lane = threadIdx.x & 63;
  if (node >= N) return;
  const f16x4* hp = (const f16x4*)(h + (size_t)node * 768 + lane * 12);
  float ss = 0.f, sd = 0.f;
  int cbase = lane * 12;
  #pragma unroll
  for (int q = 0; q < 3; q++) {
    f16x4 hv = hp[q];
    #pragma unroll
    for (int j = 0; j < 4; j++) {
      int c = cbase + q * 4 + j;
      float v = (float)hv[j];
      ss += v * a_src[c];
      sd += v * a_dst[c];
    }
  }
  const int red = (H == 8) ? 8 : 64;
  #pragma unroll
  for (int off = 1; off < red; off <<= 1) {
    ss += __shfl_xor(ss, off);
    sd += __shfl_xor(sd, off);
  }
  if (H == 8) {
    if ((lane & 7) == 0) {
      als[(size_t)node * 8 + (lane >> 3)] = ss;
      ald[(size_t)node * 8 + (lane >> 3)] = sd;
    }
  } else {
    if (lane == 0) { als[node] = ss; ald[node] = sd; }
  }
}

// ---------------- edge-parallel exp(leaky_relu(logit)) on SORTED edges ----------
// H=8 layout: ex[(half*E + e)*4 + (h&3)], half = h>>2 (half-planes so each
// half-block streams fully-consumed cachelines). H=1: ex[e].
template <int H>
__global__ __launch_bounds__(256) void k_alpha(const float* __restrict__ als,
                                               const float* __restrict__ ald,
                                               const int* __restrict__ srcs,
                                               const int* __restrict__ dsts,
                                               float* __restrict__ ex, int E) {
  const int e = blockIdx.x * 256 + threadIdx.x;
  if (e >= E) return;
  const int s = srcs[e], d = dsts[e];
  if (H == 8) {
    #pragma unroll
    for (int half = 0; half < 2; half++) {
      float4 o;
      #pragma unroll
      for (int hh = 0; hh < 4; hh++) {
        const int h = half * 4 + hh;
        float v = als[(size_t)s * 8 + h] + ald[(size_t)d * 8 + h];
        v = v > 0.f ? v : LRELU_SLOPE * v;
        ((float*)&o)[hh] = __expf(v);
      }
      *(float4*)(ex + ((size_t)half * E + e) * 4) = o;
    }
  } else {
    float v = als[s] + ald[d];
    v = v > 0.f ? v : LRELU_SLOPE * v;
    ex[e] = __expf(v);
  }
}

// ---------------- per-node zinv from ex (half-plane layout) ----------------
template <int H>
__global__ __launch_bounds__(256) void k_z(const float* __restrict__ ex,
                                           const int* __restrict__ starts,
                                           float* __restrict__ zinv, int N, int E) {
  int node = blockIdx.x * 4 + (threadIdx.x >> 6);
  int lane = threadIdx.x & 63;
  if (node >= N) return;
  const int start = starts[node];
  const int deg = starts[node + 1] - start;
  float z = 0.f;
  if (H == 8) {
    const int h = lane & 7;
    const size_t pbase = (size_t)(h >> 2) * E;
    const int hh = h & 3;
    for (int j = lane >> 3; j < deg; j += 8)
      z += ex[(pbase + start + j) * 4 + hh];
    #pragma unroll
    for (int off = 8; off < 64; off <<= 1) z += __shfl_xor(z, off);
    if (lane < 8) zinv[(size_t)node * 8 + h] = 1.f / (z + 1e-16f);
  } else {
    for (int j = lane; j < deg; j += 64) z += ex[start + j];
    #pragma unroll
    for (int off = 1; off < 64; off <<= 1) z += __shfl_xor(z, off);
    if (lane == 0) zinv[node] = 1.f / (z + 1e-16f);
  }
}

// ---------------- fused aggregation, channel-half split ----------------
// bid = n*2 + half: half 0 -> even XCDs, half 1 -> odd; per-XCD h working set
// = one 15MB channel-half. Structure = round-4 proven kernel (192 thr, LDS-staged
// weights, coalesced gather) with f16x2 loads; exp/z hoisted to k_alpha/k_z.
template <int H, bool FINAL>
__global__ __launch_bounds__(192) void k_agg3(
    const f16* __restrict__ h, const float* __restrict__ ex,
    const float* __restrict__ zinv, const int* __restrict__ starts,
    const int* __restrict__ src_sorted, const float* __restrict__ bias,
    void* __restrict__ outv, int nvalid, int E) {
  const int n = blockIdx.x >> 1;
  const int half = blockIdx.x & 1;
  const int t = threadIdx.x;
  if (n >= nvalid) return;
  constexpr int HH = (H == 8) ? 4 : 1;  // heads in this half
  __shared__ float s_ex[256 * HH];
  __shared__ int s_src[256];
  const int start = starts[n];
  const int deg = starts[n + 1] - start;
  const int c2 = half * 384 + t * 2;            // channel base (f16x2)
  const int myh = (H == 8) ? (c2 / 96) : 0;     // global head
  const int lh = (H == 8) ? (myh - half * 4) : 0;
  const float* exp_ = (H == 8) ? (ex + (size_t)half * E * 4) : ex;

  float ax = 0.f, ay = 0.f;

  for (int cb = 0; cb < deg; cb += 256) {
    const int cnt = min(256, deg - cb);
    for (int e = t; e < cnt; e += 192) s_src[e] = src_sorted[start + cb + e];
    for (int idx = t; idx < cnt * HH; idx += 192)
      s_ex[idx] = exp_[(size_t)(start + cb) * HH + idx];
    __syncthreads();
    for (int e = 0; e < cnt; e++) {
      const f16x2 hv = *(const f16x2*)(h + (size_t)s_src[e] * 768 + c2);
      const float a = s_ex[e * HH + lh];
      ax += a * (float)hv[0];
      ay += a * (float)hv[1];
    }
    __syncthreads();
  }

  const float zi = zinv[(size_t)n * H + myh];
  const float2 bv = *(const float2*)(bias + c2);
  float v0 = ax * zi + bv.x;
  float v1 = ay * zi + bv.y;
  if (FINAL) {
    float2 o = {v0, v1};
    *(float2*)((float*)outv + (size_t)n * 768 + c2) = o;
  } else {
    v0 = v0 > 0.f ? v0 : expm1f(v0);
    v1 = v1 > 0.f ? v1 : expm1f(v1);
    f16x2 o;
    o[0] = (f16)v0; o[1] = (f16)v1;
    *(f16x2*)((f16*)outv + (size_t)n * 768 + c2) = o;
  }
}

// ---------------- launcher ----------------
extern "C" void kernel_launch(void* const* d_in, const int* in_sizes, int n_in,
                              void* d_out, int out_size, void* d_ws, size_t ws_size,
                              hipStream_t stream) {
  const float* x   = (const float*)d_in[0];
  const int*   ei  = (const int*)d_in[1];
  const float* W1  = (const float*)d_in[2];
  const float* as1 = (const float*)d_in[3];
  const float* ad1 = (const float*)d_in[4];
  const float* b1  = (const float*)d_in[5];
  const float* W2  = (const float*)d_in[6];
  const float* as2 = (const float*)d_in[7];
  const float* ad2 = (const float*)d_in[8];
  const float* b2  = (const float*)d_in[9];

  const int N = in_sizes[0] / 768;
  const int E = in_sizes[1] / 2;
  const int Mpad = (N + 127) & ~127;
  const int* srcp = ei;
  const int* dstp = ei + E;

  char* p = (char*)d_ws;
  auto alloc = [&](size_t b) { char* r = p; p += (b + 255) & ~(size_t)255; return r; };
  f16*   bufX   = (f16*)alloc((size_t)Mpad * 768 * sizeof(f16));  // x_h, then out1
  f16*   bufH   = (f16*)alloc((size_t)Mpad * 768 * sizeof(f16));  // h1, then h2
  f16*   Wt1    = (f16*)alloc((size_t)768 * 768 * sizeof(f16));
  f16*   Wt2    = (f16*)alloc((size_t)768 * 768 * sizeof(f16));
  float* ex     = (float*)alloc((size_t)8 * E * sizeof(float));   // 2 half-planes x E x 4
  float* als1   = (float*)alloc((size_t)N * 8 * sizeof(float));
  float* ald1   = (float*)alloc((size_t)N * 8 * sizeof(float));
  float* zinv1  = (float*)alloc((size_t)N * 8 * sizeof(float));
  float* als2   = (float*)alloc((size_t)N * sizeof(float));
  float* ald2   = (float*)alloc((size_t)N * sizeof(float));
  float* zinv2  = (float*)alloc((size_t)N * sizeof(float));
  int*   counts = (int*)alloc((size_t)N * sizeof(int));
  int*   starts = (int*)alloc(((size_t)N + 1) * sizeof(int));
  int*   cursor = (int*)alloc((size_t)N * sizeof(int));
  int*   srcs   = (int*)alloc((size_t)E * sizeof(int));
  int*   dsts   = (int*)alloc((size_t)E * sizeof(int));

  // CSR build
  hipMemsetAsync(counts, 0, (size_t)N * sizeof(int), stream);
  k_hist<<<dim3(512), dim3(256), 0, stream>>>(dstp, E, counts);
  k_scan_block<<<dim3(1), dim3(1024), 0, stream>>>(counts, starts, cursor, N);
  k_fill<<<dim3(512), dim3(256), 0, stream>>>(srcp, dstp, E, cursor, srcs, dsts);

  // prep
  k_prep_xh<<<dim3(1024), dim3(256), 0, stream>>>(x, bufX, N, Mpad);
  k_transpose_w2<<<dim3(24, 24, 2), dim3(256), 0, stream>>>(W1, W2, Wt1, Wt2);

  const int eb = (E + 255) / 256;

  // layer 1
  k_gemm_f16<<<dim3(Mpad / 128, 6), dim3(256), 0, stream>>>(bufX, Wt1, bufH, N);
  k_al<8><<<dim3((N + 3) / 4), dim3(256), 0, stream>>>(bufH, as1, ad1, als1, ald1, N);
  k_alpha<8><<<dim3(eb), dim3(256), 0, stream>>>(als1, ald1, srcs, dsts, ex, E);
  k_z<8><<<dim3((N + 3) / 4), dim3(256), 0, stream>>>(ex, starts, zinv1, N, E);
  k_agg3<8, false><<<dim3(N * 2), dim3(192), 0, stream>>>(
      bufH, ex, zinv1, starts, srcs, b1, bufX, N, E);

  // layer 2 (bufX pad rows still hold k_prep_xh zeros)
  k_gemm_f16<<<dim3(Mpad / 128, 6), dim3(256), 0, stream>>>(bufX, Wt2, bufH, N);
  k_al<1><<<dim3((N + 3) / 4), dim3(256), 0, stream>>>(bufH, as2, ad2, als2, ald2, N);
  k_alpha<1><<<dim3(eb), dim3(256), 0, stream>>>(als2, ald2, srcs, dsts, ex, E);
  k_z<1><<<dim3((N + 3) / 4), dim3(256), 0, stream>>>(ex, starts, zinv2, N, E);
  k_agg3<1, true><<<dim3(N * 2), dim3(192), 0, stream>>>(
      bufH, ex, zinv2, starts, srcs, b2, d_out, N, E);
}

// Round 11
// 320.112 us; speedup vs baseline: 9.0445x; 1.1378x over previous
//
#include <hip/hip_runtime.h>
#include <cstdint>
#include <cstddef>

typedef _Float16 f16;
typedef _Float16 f16x4 __attribute__((ext_vector_type(4)));
typedef _Float16 f16x8 __attribute__((ext_vector_type(8)));
typedef float f32x4 __attribute__((ext_vector_type(4)));

#define LRELU_SLOPE 0.2f

#define GLL16(g, l)                                                          \
  __builtin_amdgcn_global_load_lds(                                          \
      (const __attribute__((address_space(1))) void*)(g),                    \
      (__attribute__((address_space(3))) void*)(l), 16, 0, 0)

// ---------------- prep: x (f32) -> x_h (f16), padded rows zeroed ----------------
__global__ __launch_bounds__(256) void k_prep_xh(const float* __restrict__ x,
                                                 f16* __restrict__ xh,
                                                 int nvalid, int npad) {
  int total = npad * 192;
  for (int idx = blockIdx.x * blockDim.x + threadIdx.x; idx < total;
       idx += gridDim.x * blockDim.x) {
    int row = idx / 192;
    f16x4 o;
    if (row < nvalid) {
      const float4 v = *(const float4*)(x + (size_t)idx * 4);
      o[0] = (f16)v.x; o[1] = (f16)v.y; o[2] = (f16)v.z; o[3] = (f16)v.w;
    } else {
      o[0] = (f16)0.f; o[1] = (f16)0.f; o[2] = (f16)0.f; o[3] = (f16)0.f;
    }
    *(f16x4*)(xh + (size_t)idx * 4) = o;
  }
}

// ---------------- both W [768][768] f32 -> Wt [n][k] f16, one launch ----------------
__global__ __launch_bounds__(256) void k_transpose_w2(const float* __restrict__ W1,
                                                      const float* __restrict__ W2,
                                                      f16* __restrict__ Wt1,
                                                      f16* __restrict__ Wt2) {
  const float* W = blockIdx.z ? W2 : W1;
  f16* Wt = blockIdx.z ? Wt2 : Wt1;
  __shared__ float tile[32][33];
  int bn = blockIdx.x * 32;
  int bk = blockIdx.y * 32;
  int tx = threadIdx.x & 31, ty = threadIdx.x >> 5;
  #pragma unroll
  for (int r = ty; r < 32; r += 8)
    tile[r][tx] = W[(size_t)(bk + r) * 768 + bn + tx];
  __syncthreads();
  #pragma unroll
  for (int r = ty; r < 32; r += 8)
    Wt[(size_t)(bn + r) * 768 + bk + tx] = (f16)tile[tx][r];
}

// ---------------- CSR build ----------------
__global__ void k_hist(const int* __restrict__ dst, int E, int* __restrict__ counts) {
  for (int e = blockIdx.x * blockDim.x + threadIdx.x; e < E;
       e += gridDim.x * blockDim.x) atomicAdd(&counts[dst[e]], 1);
}

__global__ __launch_bounds__(1024) void k_scan_block(const int* __restrict__ counts,
                                                     int* __restrict__ starts,
                                                     int* __restrict__ cursor, int n) {
  const int t = threadIdx.x;
  const int nthr = 1024;
  const int chunk = (n + nthr - 1) / nthr;
  const int base = t * chunk;
  int tsum = 0;
  for (int i = 0; i < chunk; i++) {
    int idx = base + i;
    if (idx < n) tsum += counts[idx];
  }
  int lane = t & 63, wv = t >> 6;
  int s = tsum;
  #pragma unroll
  for (int off = 1; off < 64; off <<= 1) {
    int tmp = __shfl_up(s, off);
    if (lane >= off) s += tmp;
  }
  __shared__ int wsum[16];
  if (lane == 63) wsum[wv] = s;
  __syncthreads();
  int woff = 0;
  for (int w = 0; w < wv; w++) woff += wsum[w];
  int run = woff + s - tsum;
  for (int i = 0; i < chunk; i++) {
    int idx = base + i;
    if (idx < n) {
      starts[idx] = run;
      cursor[idx] = run;
      run += counts[idx];
    }
  }
  if (t == nthr - 1) starts[n] = run;
}

__global__ void k_fill(const int* __restrict__ src, const int* __restrict__ dst, int E,
                       int* __restrict__ cursor, int* __restrict__ src_sorted) {
  for (int e = blockIdx.x * blockDim.x + threadIdx.x; e < E;
       e += gridDim.x * blockDim.x) {
    int slot = atomicAdd(&cursor[dst[e]], 1);
    src_sorted[slot] = src[e];
  }
}

// ---------------- fp16 MFMA GEMM: BK=64, double-buffered global_load_lds --------
// T3-lite 2-phase (catalog recipe, m230/m248): STAGE(next) issued BEFORE compute,
// raw s_barrier + LATE vmcnt(0) per step (no per-step full drain on the critical
// path). Bijective chunked XCD swizzle (m204), m-major: all 6 bn of an m-tile on
// one XCD -> A-panel fetched over fabric once, L2-reused 6x.
__global__ __launch_bounds__(256) void k_gemm_f16(const f16* __restrict__ A,
                                                  const f16* __restrict__ Bt,
                                                  f16* __restrict__ C, int Mvalid) {
  __shared__ __align__(16) f16 As[2][8192];  // [buf][128*64]
  __shared__ __align__(16) f16 Bs[2][8192];
  const int K = 768;
  const int tid = threadIdx.x;

  // bijective XCD swizzle: xcd = orig%8 gets a contiguous wgid chunk (m204)
  const int nwg = gridDim.x;
  const int orig = blockIdx.x;
  const int q = nwg >> 3, r = nwg & 7;
  const int xcd = orig & 7;
  const int wgid = (xcd < r ? xcd * (q + 1) : r * (q + 1) + (xcd - r) * q) + (orig >> 3);
  const int bm = (wgid / 6) * 128;
  const int bn = (wgid - (wgid / 6) * 6) * 128;

  const int lane = tid & 63;
  const int wave = tid >> 6;
  const int wr = (wave >> 1) * 64;
  const int wc = (wave & 1) * 64;

  // staging: pass p, cell = p*256+tid; row = cell>>3; logical chunk = (cell&7)^(row&7)
  size_t goffA[4], goffB[4];
  #pragma unroll
  for (int p = 0; p < 4; p++) {
    const int cell = p * 256 + tid;
    const int row = cell >> 3;
    const int cl = (cell & 7) ^ (row & 7);
    goffA[p] = (size_t)(bm + row) * K + cl * 8;
    goffB[p] = (size_t)(bn + row) * K + cl * 8;
  }

  f32x4 acc[4][4];
  const f32x4 vzero = {0.f, 0.f, 0.f, 0.f};
  #pragma unroll
  for (int i = 0; i < 4; i++)
    #pragma unroll
    for (int j = 0; j < 4; j++) acc[i][j] = vzero;

  const int fr = lane & 15;
  const int fq = lane >> 4;

  #define STAGE(buf, k0)                                                      \
    do {                                                                      \
      _Pragma("unroll")                                                       \
      for (int p = 0; p < 4; p++) {                                           \
        GLL16(A + goffA[p] + (k0), &As[buf][p * 2048 + wave * 512]);          \
        GLL16(Bt + goffB[p] + (k0), &Bs[buf][p * 2048 + wave * 512]);         \
      }                                                                       \
    } while (0)

  // prologue
  STAGE(0, 0);
  asm volatile("s_waitcnt vmcnt(0)" ::: "memory");
  __builtin_amdgcn_s_barrier();

  const int NT = K / 64;  // 12
  int cur = 0;
  for (int t = 0; t < NT; t++) {
    if (t + 1 < NT) STAGE(cur ^ 1, (t + 1) * 64);
    // compute tile t from buf cur (compiler inserts lgkmcnt for ds_read->MFMA)
    #pragma unroll
    for (int ks = 0; ks < 2; ks++) {
      f16x8 af[4], bf[4];
      #pragma unroll
      for (int i = 0; i < 4; i++) {
        const int rr = wr + i * 16 + fr;
        const int phys = (ks * 4 + fq) ^ (rr & 7);
        af[i] = *(const f16x8*)(&As[cur][rr * 64 + phys * 8]);
      }
      #pragma unroll
      for (int j = 0; j < 4; j++) {
        const int rr = wc + j * 16 + fr;
        const int phys = (ks * 4 + fq) ^ (rr & 7);
        bf[j] = *(const f16x8*)(&Bs[cur][rr * 64 + phys * 8]);
      }
      #pragma unroll
      for (int i = 0; i < 4; i++)
        #pragma unroll
        for (int j = 0; j < 4; j++)
          acc[i][j] = __builtin_amdgcn_mfma_f32_16x16x32_f16(af[i], bf[j], acc[i][j], 0, 0, 0);
    }
    // late drain: next tile's loads had the whole compute phase to land
    asm volatile("s_waitcnt vmcnt(0)" ::: "memory");
    __builtin_amdgcn_s_barrier();
    cur ^= 1;
  }
  #undef STAGE

  #pragma unroll
  for (int i = 0; i < 4; i++) {
    #pragma unroll
    for (int j = 0; j < 4; j++) {
      const int col = bn + wc + j * 16 + fr;
      #pragma unroll
      for (int rg = 0; rg < 4; rg++) {
        const int row = bm + wr + i * 16 + fq * 4 + rg;
        if (row < Mvalid) C[(size_t)row * 768 + col] = (f16)acc[i][j][rg];
      }
    }
  }
}

// ---------------- attention logits: al[n][h] = sum_c h[n][h*C+c]*a[h][c] ----------
template <int H>
__global__ __launch_bounds__(256) void k_al(const f16* __restrict__ h,
                                            const float* __restrict__ a_src,
                                            const float* __restrict__ a_dst,
                                            float* __restrict__ als,
                                            float* __restrict__ ald, int N) {
  int node = blockIdx.x * 4 + (threadIdx.x >> 6);
  int lane = threadIdx.x & 63;
  if (node >= N) return;
  const f16x4* hp = (const f16x4*)(h + (size_t)node * 768 + lane * 12);
  float ss = 0.f, sd = 0.f;
  int cbase = lane * 12;
  #pragma unroll
  for (int q = 0; q < 3; q++) {
    f16x4 hv = hp[q];
    #pragma unroll
    for (int j = 0; j < 4; j++) {
      int c = cbase + q * 4 + j;
      float v = (float)hv[j];
      ss += v * a_src[c];
      sd += v * a_dst[c];
    }
  }
  const int red = (H == 8) ? 8 : 64;
  #pragma unroll
  for (int off = 1; off < red; off <<= 1) {
    ss += __shfl_xor(ss, off);
    sd += __shfl_xor(sd, off);
  }
  if (H == 8) {
    if ((lane & 7) == 0) {
      als[(size_t)node * 8 + (lane >> 3)] = ss;
      ald[(size_t)node * 8 + (lane >> 3)] = sd;
    }
  } else {
    if (lane == 0) { als[node] = ss; ald[node] = sd; }
  }
}

// ---------------- fused segment softmax + aggregation + bias (+ELU) ----------------
// round-4/6 proven structure (73.5us): 192 threads, coalesced full-row gather,
// LDS-staged alphas. Untouched.
template <int H, bool FINAL>
__global__ __launch_bounds__(192) void k_aggregate(
    const f16* __restrict__ h, const float* __restrict__ als,
    const float* __restrict__ ald, const int* __restrict__ starts,
    const int* __restrict__ src_sorted, const float* __restrict__ bias,
    void* __restrict__ outv, int nvalid) {
  const int n = blockIdx.x;
  const int t = threadIdx.x;
  if (n >= nvalid) return;
  __shared__ float s_ex[256 * H];
  __shared__ int s_src[256];
  __shared__ float s_zp[3][H];
  const int start = starts[n];
  const int deg = starts[n + 1] - start;
  const int lane = t & 63, wv = t >> 6;
  const int hA = (H == 8) ? (t & 7) : 0;
  const int myh = (H == 8) ? (t / 24) : 0;
  const float ald_A = ald[(size_t)n * H + hA];

  float zpart = 0.f;
  float4 acc = {0.f, 0.f, 0.f, 0.f};

  for (int cb = 0; cb < deg; cb += 256) {
    const int cnt = min(256, deg - cb);
    for (int idx = t; idx < cnt * H; idx += 192) {
      const int e = (H == 8) ? (idx >> 3) : idx;
      const int s = src_sorted[start + cb + e];
      if (H == 1 || (idx & 7) == 0) s_src[e] = s;
      float v = als[(size_t)s * H + hA] + ald_A;
      v = v > 0.f ? v : LRELU_SLOPE * v;
      const float ex = __expf(v);
      s_ex[idx] = ex;
      zpart += ex;
    }
    __syncthreads();
    for (int e = 0; e < cnt; e++) {
      const f16x4 hv = *(const f16x4*)(h + (size_t)s_src[e] * 768 + 4 * t);
      const float a = s_ex[e * H + myh];
      acc.x += a * (float)hv[0];
      acc.y += a * (float)hv[1];
      acc.z += a * (float)hv[2];
      acc.w += a * (float)hv[3];
    }
    __syncthreads();
  }

  if (H == 8) {
    #pragma unroll
    for (int off = 8; off < 64; off <<= 1) zpart += __shfl_xor(zpart, off);
    if (lane < 8) s_zp[wv][lane] = zpart;
  } else {
    #pragma unroll
    for (int off = 1; off < 64; off <<= 1) zpart += __shfl_xor(zpart, off);
    if (lane == 0) s_zp[wv][0] = zpart;
  }
  __syncthreads();
  const float z = s_zp[0][myh] + s_zp[1][myh] + s_zp[2][myh];
  const float inv = 1.f / (z + 1e-16f);

  const float4 bv = *(const float4*)(bias + 4 * t);
  float v0 = acc.x * inv + bv.x;
  float v1 = acc.y * inv + bv.y;
  float v2 = acc.z * inv + bv.z;
  float v3 = acc.w * inv + bv.w;
  if (!FINAL) {
    v0 = v0 > 0.f ? v0 : expm1f(v0);
    v1 = v1 > 0.f ? v1 : expm1f(v1);
    v2 = v2 > 0.f ? v2 : expm1f(v2);
    v3 = v3 > 0.f ? v3 : expm1f(v3);
    f16x4 o;
    o[0] = (f16)v0; o[1] = (f16)v1; o[2] = (f16)v2; o[3] = (f16)v3;
    *(f16x4*)((f16*)outv + (size_t)n * 768 + 4 * t) = o;
  } else {
    float4 o = {v0, v1, v2, v3};
    *(float4*)((float*)outv + (size_t)n * 768 + 4 * t) = o;
  }
}

// ---------------- launcher ----------------
extern "C" void kernel_launch(void* const* d_in, const int* in_sizes, int n_in,
                              void* d_out, int out_size, void* d_ws, size_t ws_size,
                              hipStream_t stream) {
  const float* x   = (const float*)d_in[0];
  const int*   ei  = (const int*)d_in[1];
  const float* W1  = (const float*)d_in[2];
  const float* as1 = (const float*)d_in[3];
  const float* ad1 = (const float*)d_in[4];
  const float* b1  = (const float*)d_in[5];
  const float* W2  = (const float*)d_in[6];
  const float* as2 = (const float*)d_in[7];
  const float* ad2 = (const float*)d_in[8];
  const float* b2  = (const float*)d_in[9];

  const int N = in_sizes[0] / 768;
  const int E = in_sizes[1] / 2;
  const int Mpad = (N + 127) & ~127;
  const int* srcp = ei;
  const int* dstp = ei + E;

  char* p = (char*)d_ws;
  auto alloc = [&](size_t b) { char* r = p; p += (b + 255) & ~(size_t)255; return r; };
  f16*   bufX   = (f16*)alloc((size_t)Mpad * 768 * sizeof(f16));  // x_h, then out1
  f16*   bufH   = (f16*)alloc((size_t)Mpad * 768 * sizeof(f16));  // h1, then h2
  f16*   Wt1    = (f16*)alloc((size_t)768 * 768 * sizeof(f16));
  f16*   Wt2    = (f16*)alloc((size_t)768 * 768 * sizeof(f16));
  float* als1   = (float*)alloc((size_t)N * 8 * sizeof(float));
  float* ald1   = (float*)alloc((size_t)N * 8 * sizeof(float));
  float* als2   = (float*)alloc((size_t)N * sizeof(float));
  float* ald2   = (float*)alloc((size_t)N * sizeof(float));
  int*   counts = (int*)alloc((size_t)N * sizeof(int));
  int*   starts = (int*)alloc(((size_t)N + 1) * sizeof(int));
  int*   cursor = (int*)alloc((size_t)N * sizeof(int));
  int*   srcs   = (int*)alloc((size_t)E * sizeof(int));

  // CSR build
  hipMemsetAsync(counts, 0, (size_t)N * sizeof(int), stream);
  k_hist<<<dim3(512), dim3(256), 0, stream>>>(dstp, E, counts);
  k_scan_block<<<dim3(1), dim3(1024), 0, stream>>>(counts, starts, cursor, N);
  k_fill<<<dim3(512), dim3(256), 0, stream>>>(srcp, dstp, E, cursor, srcs);

  // prep
  k_prep_xh<<<dim3(1024), dim3(256), 0, stream>>>(x, bufX, N, Mpad);
  k_transpose_w2<<<dim3(24, 24, 2), dim3(256), 0, stream>>>(W1, W2, Wt1, Wt2);

  const int nwg = (Mpad / 128) * 6;

  // layer 1
  k_gemm_f16<<<dim3(nwg), dim3(256), 0, stream>>>(bufX, Wt1, bufH, N);
  k_al<8><<<dim3((N + 3) / 4), dim3(256), 0, stream>>>(bufH, as1, ad1, als1, ald1, N);
  k_aggregate<8, false><<<dim3(N), dim3(192), 0, stream>>>(bufH, als1, ald1, starts, srcs, b1, bufX, N);

  // layer 2 (bufX pad rows still hold k_prep_xh zeros)
  k_gemm_f16<<<dim3(nwg), dim3(256), 0, stream>>>(bufX, Wt2, bufH, N);
  k_al<1><<<dim3((N + 3) / 4), dim3(256), 0, stream>>>(bufH, as2, ad2, als2, ald2, N);
  k_aggregate<1, true><<<dim3(N), dim3(192), 0, stream>>>(bufH, als2, ald2, starts, srcs, b2, d_out, N);
}